// Round 1
// baseline (94.288 us; speedup 1.0000x reference)
//
#include <hip/hip_runtime.h>

// out[2048,64] = inputs[2048,2000] @ emb[2000,64], fp32.
// Decomposition: wave = 8 rows x 64 cols (lane = column d).
// Split V into 8 chunks of 250 for grid parallelism; partials via atomicAdd.

#define Bn 2048
#define Vn 2000
#define Dn 64
#define RW 8                     // rows per wave (register blocking -> emb reuse)
#define WAVES 4
#define ROWS_PER_BLOCK (RW * WAVES)   // 32
#define NCHUNK 8
#define VC (Vn / NCHUNK)         // 250

__global__ __launch_bounds__(256, 2)
void embw_gemm(const float* __restrict__ in, const float* __restrict__ emb,
               float* __restrict__ out) {
    const int lane = threadIdx.x & 63;
    // force wave-uniform row base into SGPRs so input loads scalarize (s_load)
    const int wid  = __builtin_amdgcn_readfirstlane(threadIdx.x >> 6);
    const int bg   = blockIdx.x / NCHUNK;   // row group
    const int ch   = blockIdx.x % NCHUNK;   // v chunk
    const int row0 = bg * ROWS_PER_BLOCK + wid * RW;
    const int v0   = ch * VC;

    // per-row input pointers (wave-uniform -> scalar loads)
    const float* rp[RW];
#pragma unroll
    for (int r = 0; r < RW; ++r)
        rp[r] = in + (size_t)(row0 + r) * Vn + v0;

    // emb column pointer for this lane
    const float* ep = emb + (size_t)v0 * Dn + lane;

    float acc[RW];
#pragma unroll
    for (int r = 0; r < RW; ++r) acc[r] = 0.0f;

    // 250 = 25 * 10 ; unroll 10 gives load-prefetch distance for L2 latency
#pragma unroll 1
    for (int vv = 0; vv < VC; vv += 10) {
        float e[10];
#pragma unroll
        for (int u = 0; u < 10; ++u)
            e[u] = ep[(size_t)(vv + u) * Dn];   // coalesced 256B/wave, L2-hit
#pragma unroll
        for (int u = 0; u < 10; ++u) {
#pragma unroll
            for (int r = 0; r < RW; ++r)
                acc[r] = fmaf(rp[r][vv + u], e[u], acc[r]);  // scalar x vector
        }
    }

#pragma unroll
    for (int r = 0; r < RW; ++r)
        atomicAdd(&out[(size_t)(row0 + r) * Dn + lane], acc[r]);
}

extern "C" void kernel_launch(void* const* d_in, const int* in_sizes, int n_in,
                              void* d_out, int out_size, void* d_ws, size_t ws_size,
                              hipStream_t stream) {
    const float* in  = (const float*)d_in[0];   // (2048, 2000) fp32
    const float* emb = (const float*)d_in[1];   // (2000, 64)  fp32
    float* out = (float*)d_out;                 // (2048, 64)  fp32

    // d_out is re-poisoned to 0xAA before every launch; zero it (atomic accumulate)
    hipMemsetAsync(out, 0, (size_t)out_size * sizeof(float), stream);

    const int grid = (Bn / ROWS_PER_BLOCK) * NCHUNK;   // 64 * 8 = 512
    embw_gemm<<<grid, 256, 0, stream>>>(in, emb, out);
}

// Round 2
// 86.058 us; speedup vs baseline: 1.0956x; 1.0956x over previous
//
#include <hip/hip_runtime.h>

// out[2048,64] = inputs[2048,2000] @ emb[2000,64], fp32 (dense GEMM view).
// Wave = 8 rows x 64 cols (lane = d). Inputs staged in LDS (coalesced global
// loads), consumed as wave-broadcast ds_read_b128. emb read from L2 (512 KB,
// fully cached), 256B coalesced per load. K split 8-way across blocks,
// combined via fp32 atomicAdd.

#define Bn 2048
#define Vn 2000
#define Dn 64
#define RW 8                      // rows per wave
#define WAVES 4
#define ROWS (RW * WAVES)         // 32 rows per block
#define NCHUNK 8
#define KC (Vn / NCHUNK)          // 250
#define LDK 252                   // padded LDS row stride (1008B, 16B-aligned)

__global__ __launch_bounds__(256, 2)
void embw(const float* __restrict__ in, const float* __restrict__ emb,
          float* __restrict__ out) {
    __shared__ float lds[ROWS][LDK];
    const int lane = threadIdx.x & 63;
    const int wid  = threadIdx.x >> 6;
    const int bg   = blockIdx.x / NCHUNK;     // row-group
    const int ch   = blockIdx.x - bg * NCHUNK; // k-chunk
    const int row0 = bg * ROWS + wid * RW;
    const int k0   = ch * KC;

    // --- stage this wave's 8 rows (coalesced 256B/instr) ---
    const float* gsrc = in + (size_t)row0 * Vn + k0;
#pragma unroll
    for (int r = 0; r < RW; ++r) {
        const float* src = gsrc + (size_t)r * Vn;
        float* dst = lds[wid * RW + r];
        for (int k = lane; k < KC; k += 64)
            dst[k] = src[k];
    }
    __syncthreads();   // cheap (once per kernel); guarantees LDS visibility

    const float* ep = emb + (size_t)k0 * Dn + lane;
    float acc[RW] = {0.f, 0.f, 0.f, 0.f, 0.f, 0.f, 0.f, 0.f};

    // --- main loop: 248 k's in steps of 8; explicit 8-deep load batches ---
#pragma unroll 1
    for (int k = 0; k < 248; k += 8) {
        float e[8];
#pragma unroll
        for (int u = 0; u < 8; ++u)
            e[u] = ep[(k + u) * Dn];          // 8 independent L2 loads in flight
        float4 a[RW], b[RW];
#pragma unroll
        for (int r = 0; r < RW; ++r) {
            a[r] = *(const float4*)&lds[wid * RW + r][k];     // broadcast b128
            b[r] = *(const float4*)&lds[wid * RW + r][k + 4];
        }
#pragma unroll
        for (int r = 0; r < RW; ++r) {
            acc[r] = fmaf(a[r].x, e[0], acc[r]);
            acc[r] = fmaf(a[r].y, e[1], acc[r]);
            acc[r] = fmaf(a[r].z, e[2], acc[r]);
            acc[r] = fmaf(a[r].w, e[3], acc[r]);
            acc[r] = fmaf(b[r].x, e[4], acc[r]);
            acc[r] = fmaf(b[r].y, e[5], acc[r]);
            acc[r] = fmaf(b[r].z, e[6], acc[r]);
            acc[r] = fmaf(b[r].w, e[7], acc[r]);
        }
    }
    // tail: k = 248, 249
#pragma unroll
    for (int k = 248; k < KC; ++k) {
        float e = ep[k * Dn];
#pragma unroll
        for (int r = 0; r < RW; ++r)
            acc[r] = fmaf(lds[wid * RW + r][k], e, acc[r]);
    }

#pragma unroll
    for (int r = 0; r < RW; ++r)
        atomicAdd(&out[(size_t)(row0 + r) * Dn + lane], acc[r]);
}

extern "C" void kernel_launch(void* const* d_in, const int* in_sizes, int n_in,
                              void* d_out, int out_size, void* d_ws, size_t ws_size,
                              hipStream_t stream) {
    const float* in  = (const float*)d_in[0];   // (2048, 2000) fp32
    const float* emb = (const float*)d_in[1];   // (2000, 64)  fp32
    float* out = (float*)d_out;                 // (2048, 64)  fp32

    hipMemsetAsync(out, 0, (size_t)out_size * sizeof(float), stream);

    const int grid = (Bn / ROWS) * NCHUNK;      // 64 * 8 = 512 blocks
    embw<<<grid, 256, 0, stream>>>(in, emb, out);
}

// Round 7
// 83.934 us; speedup vs baseline: 1.1234x; 1.0253x over previous
//
#include <hip/hip_runtime.h>

// out[2048,64] = inputs[2048,2000] @ emb[2000,64], fp32 dense GEMM view.
// K1: grid (32 row-blocks x 16 k-chunks); wave = 16 rows x 64 cols (lane=d).
//     A rows staged in LDS (padded stride 128 -> aligned ds_read_b128,
//     broadcast reads are conflict-free). emb streamed from L2 with explicit
//     8-deep prefetch double-buffer. Partials -> ws (NO atomics).
// K2: reduce 16 partials -> out.

#define Bn 2048
#define Vn 2000
#define Dn 64
#define RW 16                  // rows per wave
#define WAVES 4
#define ROWS (RW * WAVES)      // 64 rows per block
#define KCH 16                 // k-chunks
#define KC 125                 // Vn / KCH
#define LDK 128                // padded LDS row stride (512B -> 16B aligned)

__global__ __launch_bounds__(256, 2)
void embw_part(const float* __restrict__ in, const float* __restrict__ emb,
               float* __restrict__ part) {
    __shared__ float lds[ROWS][LDK];
    const int lane = threadIdx.x & 63;
    const int wid  = threadIdx.x >> 6;
    const int bg   = blockIdx.x / KCH;
    const int ch   = blockIdx.x - bg * KCH;
    const int wrow = wid * RW;
    const int row0 = bg * ROWS + wrow;
    const int k0   = ch * KC;

    // ---- stage this wave's 16 rows x 125 f32 (coalesced dword loads) ----
    {
        const float* src = in + (size_t)row0 * Vn + k0;
#pragma unroll
        for (int r = 0; r < RW; ++r) {
            const float* s = src + (size_t)r * Vn;
            lds[wrow + r][lane] = s[lane];                       // k = 0..63
            if (lane < KC - 64)                                  // k = 64..124
                lds[wrow + r][lane + 64] = s[lane + 64];
        }
    }
    __syncthreads();

    const float* ep = emb + (size_t)k0 * Dn + lane;   // E[k][lane], L2-hot
    float acc[RW];
#pragma unroll
    for (int r = 0; r < RW; ++r) acc[r] = 0.f;

    float e[8];
#pragma unroll
    for (int u = 0; u < 8; ++u) e[u] = ep[u * Dn];

    // ---- main: k = 0..111 with prefetch of k+8; peel k=112 (no prefetch) ----
#pragma unroll 1
    for (int k = 0; k < 112; k += 8) {
        float en[8];
#pragma unroll
        for (int u = 0; u < 8; ++u) en[u] = ep[(k + 8 + u) * Dn];  // in flight
#pragma unroll
        for (int r = 0; r < RW; ++r) {
            float4 a = *(const float4*)&lds[wrow + r][k];
            float4 b = *(const float4*)&lds[wrow + r][k + 4];
            acc[r] = fmaf(a.x, e[0], acc[r]);
            acc[r] = fmaf(a.y, e[1], acc[r]);
            acc[r] = fmaf(a.z, e[2], acc[r]);
            acc[r] = fmaf(a.w, e[3], acc[r]);
            acc[r] = fmaf(b.x, e[4], acc[r]);
            acc[r] = fmaf(b.y, e[5], acc[r]);
            acc[r] = fmaf(b.z, e[6], acc[r]);
            acc[r] = fmaf(b.w, e[7], acc[r]);
        }
#pragma unroll
        for (int u = 0; u < 8; ++u) e[u] = en[u];
    }
    // peeled full step k = 112..119
#pragma unroll
    for (int r = 0; r < RW; ++r) {
        float4 a = *(const float4*)&lds[wrow + r][112];
        float4 b = *(const float4*)&lds[wrow + r][116];
        acc[r] = fmaf(a.x, e[0], acc[r]);
        acc[r] = fmaf(a.y, e[1], acc[r]);
        acc[r] = fmaf(a.z, e[2], acc[r]);
        acc[r] = fmaf(a.w, e[3], acc[r]);
        acc[r] = fmaf(b.x, e[4], acc[r]);
        acc[r] = fmaf(b.y, e[5], acc[r]);
        acc[r] = fmaf(b.z, e[6], acc[r]);
        acc[r] = fmaf(b.w, e[7], acc[r]);
    }
    // tail k = 120..124
#pragma unroll
    for (int k = 120; k < KC; ++k) {
        float ee = ep[k * Dn];
#pragma unroll
        for (int r = 0; r < RW; ++r)
            acc[r] = fmaf(lds[wrow + r][k], ee, acc[r]);
    }

    // ---- coalesced partial stores (no atomics) ----
    float* pp = part + ((size_t)ch * Bn + row0) * Dn + lane;
#pragma unroll
    for (int r = 0; r < RW; ++r)
        pp[(size_t)r * Dn] = acc[r];
}

__global__ __launch_bounds__(256, 2)
void embw_reduce(const float* __restrict__ part, float* __restrict__ out) {
    const int i = blockIdx.x * 256 + threadIdx.x;       // float4 index
    const float4* p = (const float4*)part;
    float4 s = p[i];
#pragma unroll
    for (int c = 1; c < KCH; ++c) {
        float4 t = p[(size_t)c * (Bn * Dn / 4) + i];
        s.x += t.x; s.y += t.y; s.z += t.z; s.w += t.w;
    }
    ((float4*)out)[i] = s;
}

extern "C" void kernel_launch(void* const* d_in, const int* in_sizes, int n_in,
                              void* d_out, int out_size, void* d_ws, size_t ws_size,
                              hipStream_t stream) {
    const float* in  = (const float*)d_in[0];   // (2048, 2000) fp32
    const float* emb = (const float*)d_in[1];   // (2000, 64)  fp32
    float* out  = (float*)d_out;                // (2048, 64)  fp32
    float* part = (float*)d_ws;                 // KCH * 2048 * 64 f32 = 8 MB

    const int grid1 = (Bn / ROWS) * KCH;        // 32 * 16 = 512
    embw_part<<<grid1, 256, 0, stream>>>(in, emb, part);

    const int grid2 = (Bn * Dn / 4) / 256;      // 128
    embw_reduce<<<grid2, 256, 0, stream>>>(part, out);
}

// Round 12
// 79.562 us; speedup vs baseline: 1.1851x; 1.0549x over previous
//
#include <hip/hip_runtime.h>

// out[2048,64] = inputs[2048,2000] @ emb[2000,64] (fp32), computed as a
// bf16 MFMA GEMM (error budget: threshold 1.125 >> bf16 rounding ~0.05).
// Grid: 32 m-blocks (64 rows) x 16 k-chunks (128 k, padded 2000->2048).
// Block: 256 thr / 4 waves. Stage A-chunk (fp32->bf16) and E-chunk
// TRANSPOSED (fp32->bf16) into LDS; each wave owns 16 rows x 64 cols via
// 4x mfma_f32_16x16x32_bf16 accumulators. Partials -> ws; K2 reduces.

#define Bn 2048
#define Vn 2000
#define Dn 64
#define KCH 16
#define KBLK 128            // padded K per chunk (16*128 = 2048)
#define MBLK 64
#define LSTR 136            // LDS row stride (bf16): dword-stride 68 == 4 mod 32
                            // -> 2-way bank alias on b128 frag reads (free), 16B-aligned

typedef __attribute__((ext_vector_type(8))) short bf16x8;
typedef __attribute__((ext_vector_type(4))) float f32x4;

__device__ inline unsigned short bf16r(float x) {
    union { float f; unsigned u; } c; c.f = x;
    return (unsigned short)((c.u + 0x8000u) >> 16);   // round-half-up to bf16
}

__global__ __launch_bounds__(256)
void embw_mfma(const float* __restrict__ A, const float* __restrict__ E,
               float* __restrict__ part) {
    __shared__ unsigned short Al[MBLK][LSTR];   // A chunk, bf16, row-major
    __shared__ unsigned short Et[Dn][LSTR];     // E chunk transposed: Et[d][k]

    const int t    = threadIdx.x;
    const int lane = t & 63;
    const int w    = t >> 6;
    const int kc   = blockIdx.x >> 5;           // 0..15  (k-chunk)
    const int mblk = blockIdx.x & 31;           // 0..31  (m-block)
    const int m0   = mblk * MBLK;
    const int k0   = kc * KBLK;

    // ---- stage A: 64 rows x 128 k, coalesced float4, fp32 -> bf16 ----
    {
        const int rs = t >> 5;                  // 0..7 row-in-sweep
        const int c4 = t & 31;                  // float4 col 0..31
        const int gk = k0 + c4 * 4;
        const bool real = (gk < Vn);            // 2000 % 4 == 0: float4-aligned cut
#pragma unroll
        for (int s = 0; s < 8; ++s) {
            const int row = s * 8 + rs;
            float4 v = make_float4(0.f, 0.f, 0.f, 0.f);
            if (real)
                v = *(const float4*)&A[(size_t)(m0 + row) * Vn + gk];
            unsigned lo = ((unsigned)bf16r(v.y) << 16) | bf16r(v.x);
            unsigned hi = ((unsigned)bf16r(v.w) << 16) | bf16r(v.z);
            *(uint2*)&Al[row][c4 * 4] = make_uint2(lo, hi);
        }
    }
    // ---- stage E^T: 128 k-rows x 64 d (lane = d, coalesced 256B rows) ----
    {
#pragma unroll
        for (int i = 0; i < KBLK / 4; ++i) {
            const int k  = w * (KBLK / 4) + i;  // 0..127
            const int gk = k0 + k;
            float v = (gk < Vn) ? E[(size_t)gk * Dn + lane] : 0.f;
            Et[lane][k] = bf16r(v);
        }
    }
    __syncthreads();

    // ---- MFMA: wave w owns rows [m0+w*16, +16) x all 64 cols ----
    const int fr = lane & 15;                   // frag M-row / N-col index
    const int fk = (lane >> 4) * 8;             // frag K base (contiguous 8)
    f32x4 acc0 = {0.f, 0.f, 0.f, 0.f};
    f32x4 acc1 = {0.f, 0.f, 0.f, 0.f};
    f32x4 acc2 = {0.f, 0.f, 0.f, 0.f};
    f32x4 acc3 = {0.f, 0.f, 0.f, 0.f};
#pragma unroll
    for (int ks = 0; ks < KBLK / 32; ++ks) {    // 4 K-steps
        const int kb = ks * 32 + fk;
        bf16x8 af = *(const bf16x8*)&Al[w * 16 + fr][kb];
        bf16x8 b0 = *(const bf16x8*)&Et[ 0 + fr][kb];
        bf16x8 b1 = *(const bf16x8*)&Et[16 + fr][kb];
        bf16x8 b2 = *(const bf16x8*)&Et[32 + fr][kb];
        bf16x8 b3 = *(const bf16x8*)&Et[48 + fr][kb];
        acc0 = __builtin_amdgcn_mfma_f32_16x16x32_bf16(af, b0, acc0, 0, 0, 0);
        acc1 = __builtin_amdgcn_mfma_f32_16x16x32_bf16(af, b1, acc1, 0, 0, 0);
        acc2 = __builtin_amdgcn_mfma_f32_16x16x32_bf16(af, b2, acc2, 0, 0, 0);
        acc3 = __builtin_amdgcn_mfma_f32_16x16x32_bf16(af, b3, acc3, 0, 0, 0);
    }

    // ---- write partials: C/D layout col=lane&15, row=(lane>>4)*4+q (m89) ----
    float* pp = part + ((size_t)kc * Bn + m0 + w * 16 + (lane >> 4) * 4) * Dn + fr;
#pragma unroll
    for (int q = 0; q < 4; ++q) {
        pp[(size_t)q * Dn +  0] = acc0[q];
        pp[(size_t)q * Dn + 16] = acc1[q];
        pp[(size_t)q * Dn + 32] = acc2[q];
        pp[(size_t)q * Dn + 48] = acc3[q];
    }
}

__global__ __launch_bounds__(256)
void embw_reduce(const float* __restrict__ part, float* __restrict__ out) {
    const int i = blockIdx.x * 256 + threadIdx.x;       // float4 index
    const float4* p = (const float4*)part;
    float4 s = p[i];
#pragma unroll
    for (int c = 1; c < KCH; ++c) {
        float4 tv = p[(size_t)c * (Bn * Dn / 4) + i];
        s.x += tv.x; s.y += tv.y; s.z += tv.z; s.w += tv.w;
    }
    ((float4*)out)[i] = s;
}

extern "C" void kernel_launch(void* const* d_in, const int* in_sizes, int n_in,
                              void* d_out, int out_size, void* d_ws, size_t ws_size,
                              hipStream_t stream) {
    const float* in  = (const float*)d_in[0];   // (2048, 2000) fp32
    const float* emb = (const float*)d_in[1];   // (2000, 64)  fp32
    float* out  = (float*)d_out;                // (2048, 64)  fp32
    float* part = (float*)d_ws;                 // 16 * 2048 * 64 f32 = 8 MB

    const int grid1 = 32 * KCH;                 // 512 blocks (2 per CU)
    embw_mfma<<<grid1, 256, 0, stream>>>(in, emb, part);

    const int grid2 = (Bn * Dn / 4) / 256;      // 128
    embw_reduce<<<grid2, 256, 0, stream>>>(part, out);
}